// Round 1
// baseline (62201.129 us; speedup 1.0000x reference)
//
#include <hip/hip_runtime.h>

#define T_STEPS 64
#define BATCH   128
#define HID     1024
#define VOCAB   10000

#define TM 32
#define TN 64
#define TK 64
#define NTHREADS 256

// ---------------------------------------------------------------------------
// rz kernel: rz[b, j] = tanh( sum_k A[b,k] * B[k,j] + bias[j] ),  j in [0,2H)
//   A[b,k] = k<H ? inp[b,k] : h[b,k-H]       (inp = emb gather for layer 0)
//   B[k,j] = j<H ? Wr[k,j] : Wz[k,j-H]
// ---------------------------------------------------------------------------
template<bool GATHER>
__global__ __launch_bounds__(NTHREADS)
void rz_kernel(const int* __restrict__ ids, const float* __restrict__ emb,
               const float* __restrict__ inp,
               const float* __restrict__ h,
               const float* __restrict__ Wr, const float* __restrict__ Wz,
               const float* __restrict__ br, const float* __restrict__ bz,
               float* __restrict__ rz)
{
    __shared__ float As[TM][TK + 1];
    __shared__ float Bs[TK][TN + 1];
    const int tid = threadIdx.x;
    const int tx = tid & 15;   // col group
    const int ty = tid >> 4;   // row group
    const int j0 = blockIdx.x * TN;
    const int b0 = blockIdx.y * TM;

    float acc[2][4] = {};

    for (int k0 = 0; k0 < 2 * HID; k0 += TK) {
        // stage A tile [TM][TK]
        #pragma unroll
        for (int i = 0; i < (TM * TK) / NTHREADS; ++i) {
            int e = tid + i * NTHREADS;
            int r = e >> 6, c = e & 63;
            int b = b0 + r, k = k0 + c;
            float v;
            if (k < HID) {
                if (GATHER) v = emb[(long)ids[b] * HID + k];
                else        v = inp[b * HID + k];
            } else {
                v = h[b * HID + (k - HID)];
            }
            As[r][c] = v;
        }
        // stage B tile [TK][TN]
        #pragma unroll
        for (int i = 0; i < (TK * TN) / NTHREADS; ++i) {
            int e = tid + i * NTHREADS;
            int kr = e >> 6, c = e & 63;
            int k = k0 + kr, j = j0 + c;
            float v = (j < HID) ? Wr[k * HID + j] : Wz[k * HID + (j - HID)];
            Bs[kr][c] = v;
        }
        __syncthreads();
        #pragma unroll
        for (int kk = 0; kk < TK; ++kk) {
            float a0 = As[ty][kk];
            float a1 = As[ty + 16][kk];
            #pragma unroll
            for (int c = 0; c < 4; ++c) {
                float bv = Bs[kk][tx + c * 16];
                acc[0][c] += a0 * bv;
                acc[1][c] += a1 * bv;
            }
        }
        __syncthreads();
    }

    #pragma unroll
    for (int rr = 0; rr < 2; ++rr) {
        int b = b0 + ty + rr * 16;
        #pragma unroll
        for (int c = 0; c < 4; ++c) {
            int j = j0 + tx + c * 16;
            float bias = (j < HID) ? br[j] : bz[j - HID];
            rz[b * (2 * HID) + j] = tanhf(acc[rr][c] + bias);
        }
    }
}

// ---------------------------------------------------------------------------
// g kernel: gpre[b,j] = sum_k A2[b,k] * Wg[k,j] + bg[j],  j in [0,H)
//   A2[b,k] = k<H ? inp[b,k] : r[b,k-H] * h[b,k-H]
//   h_tild = tanh(gpre); hn = (1-z)*h + z*h_tild
// ---------------------------------------------------------------------------
template<bool GATHER>
__global__ __launch_bounds__(NTHREADS)
void g_kernel(const int* __restrict__ ids, const float* __restrict__ emb,
              const float* __restrict__ inp,
              const float* __restrict__ h,
              const float* __restrict__ rz,
              const float* __restrict__ Wg, const float* __restrict__ bg,
              float* __restrict__ h_new, float* __restrict__ h1_all_t)
{
    __shared__ float As[TM][TK + 1];
    __shared__ float Bs[TK][TN + 1];
    const int tid = threadIdx.x;
    const int tx = tid & 15;
    const int ty = tid >> 4;
    const int j0 = blockIdx.x * TN;
    const int b0 = blockIdx.y * TM;

    float acc[2][4] = {};

    for (int k0 = 0; k0 < 2 * HID; k0 += TK) {
        #pragma unroll
        for (int i = 0; i < (TM * TK) / NTHREADS; ++i) {
            int e = tid + i * NTHREADS;
            int r = e >> 6, c = e & 63;
            int b = b0 + r, k = k0 + c;
            float v;
            if (k < HID) {
                if (GATHER) v = emb[(long)ids[b] * HID + k];
                else        v = inp[b * HID + k];
            } else {
                int km = k - HID;
                v = rz[b * (2 * HID) + km] * h[b * HID + km];
            }
            As[r][c] = v;
        }
        #pragma unroll
        for (int i = 0; i < (TK * TN) / NTHREADS; ++i) {
            int e = tid + i * NTHREADS;
            int kr = e >> 6, c = e & 63;
            int k = k0 + kr, j = j0 + c;
            Bs[kr][c] = Wg[k * HID + j];
        }
        __syncthreads();
        #pragma unroll
        for (int kk = 0; kk < TK; ++kk) {
            float a0 = As[ty][kk];
            float a1 = As[ty + 16][kk];
            #pragma unroll
            for (int c = 0; c < 4; ++c) {
                float bv = Bs[kk][tx + c * 16];
                acc[0][c] += a0 * bv;
                acc[1][c] += a1 * bv;
            }
        }
        __syncthreads();
    }

    #pragma unroll
    for (int rr = 0; rr < 2; ++rr) {
        int b = b0 + ty + rr * 16;
        #pragma unroll
        for (int c = 0; c < 4; ++c) {
            int j = j0 + tx + c * 16;
            float z = rz[b * (2 * HID) + HID + j];
            float ho = h[b * HID + j];
            float ht = tanhf(acc[rr][c] + bg[j]);
            float hn = (1.0f - z) * ho + z * ht;
            h_new[b * HID + j] = hn;
            if (h1_all_t) h1_all_t[b * HID + j] = hn;
        }
    }
}

// ---------------------------------------------------------------------------
// logits kernel: out[i, v] = tanh( sum_k h1_all[i,k] * Wout[k,v] + bout[v] )
//   M = T*B = 8192, N = VOCAB = 10000, K = HID
// ---------------------------------------------------------------------------
__global__ __launch_bounds__(NTHREADS)
void logits_kernel(const float* __restrict__ h1_all,
                   const float* __restrict__ Wout,
                   const float* __restrict__ bout,
                   float* __restrict__ out)
{
    __shared__ float As[TM][TK + 1];
    __shared__ float Bs[TK][TN + 1];
    const int tid = threadIdx.x;
    const int tx = tid & 15;
    const int ty = tid >> 4;
    const int j0 = blockIdx.x * TN;
    const int b0 = blockIdx.y * TM;

    float acc[2][4] = {};

    for (int k0 = 0; k0 < HID; k0 += TK) {
        #pragma unroll
        for (int i = 0; i < (TM * TK) / NTHREADS; ++i) {
            int e = tid + i * NTHREADS;
            int r = e >> 6, c = e & 63;
            As[r][c] = h1_all[(long)(b0 + r) * HID + k0 + c];
        }
        #pragma unroll
        for (int i = 0; i < (TK * TN) / NTHREADS; ++i) {
            int e = tid + i * NTHREADS;
            int kr = e >> 6, c = e & 63;
            int k = k0 + kr, j = j0 + c;
            Bs[kr][c] = (j < VOCAB) ? Wout[(long)k * VOCAB + j] : 0.0f;
        }
        __syncthreads();
        #pragma unroll
        for (int kk = 0; kk < TK; ++kk) {
            float a0 = As[ty][kk];
            float a1 = As[ty + 16][kk];
            #pragma unroll
            for (int c = 0; c < 4; ++c) {
                float bv = Bs[kk][tx + c * 16];
                acc[0][c] += a0 * bv;
                acc[1][c] += a1 * bv;
            }
        }
        __syncthreads();
    }

    #pragma unroll
    for (int rr = 0; rr < 2; ++rr) {
        long i = b0 + ty + rr * 16;
        #pragma unroll
        for (int c = 0; c < 4; ++c) {
            int j = j0 + tx + c * 16;
            if (j < VOCAB) {
                out[i * VOCAB + j] = tanhf(acc[rr][c] + bout[j]);
            }
        }
    }
}

__global__ void init_h(const float* __restrict__ hidden,
                       float* __restrict__ h0, float* __restrict__ h1)
{
    int i = blockIdx.x * blockDim.x + threadIdx.x;
    if (i < BATCH * HID) {
        h0[i] = hidden[i];
        h1[i] = hidden[BATCH * HID + i];
    }
}

__global__ void final_h(const float* __restrict__ h0, const float* __restrict__ h1,
                        float* __restrict__ out)
{
    int i = blockIdx.x * blockDim.x + threadIdx.x;
    if (i < BATCH * HID) {
        out[i] = h0[i];
        out[BATCH * HID + i] = h1[i];
    }
}

extern "C" void kernel_launch(void* const* d_in, const int* in_sizes, int n_in,
                              void* d_out, int out_size, void* d_ws, size_t ws_size,
                              hipStream_t stream)
{
    const int*   inputs = (const int*)  d_in[0];
    const float* hidden = (const float*)d_in[1];
    const float* emb    = (const float*)d_in[2];
    const float* Wr     = (const float*)d_in[3];
    const float* br     = (const float*)d_in[4];
    const float* Wz     = (const float*)d_in[5];
    const float* bz     = (const float*)d_in[6];
    const float* Wg     = (const float*)d_in[7];
    const float* bg     = (const float*)d_in[8];
    const float* Wout   = (const float*)d_in[9];
    const float* bout   = (const float*)d_in[10];
    float* out = (float*)d_out;

    const int BH  = BATCH * HID;     // 131072
    const int W1  = 2 * HID * HID;   // layer-1 weight offset

    float* ws = (float*)d_ws;
    float* h0[2] = { ws,          ws + BH };
    float* h1[2] = { ws + 2 * BH, ws + 3 * BH };
    float* rz0   = ws + 4 * BH;               // [B, 2H]
    float* rz1   = rz0 + BATCH * 2 * HID;     // [B, 2H]
    float* h1_all = rz1 + BATCH * 2 * HID;    // [T, B, H]

    init_h<<<(BH + 255) / 256, 256, 0, stream>>>(hidden, h0[0], h1[0]);

    dim3 grid_rz(2 * HID / TN, BATCH / TM);   // (32, 4)
    dim3 grid_g(HID / TN, BATCH / TM);        // (16, 4)

    int cur = 0;
    for (int t = 0; t < T_STEPS; ++t) {
        const int* ids_t = inputs + t * BATCH;
        // layer 0
        rz_kernel<true><<<grid_rz, NTHREADS, 0, stream>>>(
            ids_t, emb, nullptr, h0[cur], Wr, Wz, br, bz, rz0);
        g_kernel<true><<<grid_g, NTHREADS, 0, stream>>>(
            ids_t, emb, nullptr, h0[cur], rz0, Wg, bg, h0[1 - cur], nullptr);
        // layer 1 (inp = new h0)
        rz_kernel<false><<<grid_rz, NTHREADS, 0, stream>>>(
            nullptr, nullptr, h0[1 - cur], h1[cur],
            Wr + W1, Wz + W1, br + HID, bz + HID, rz1);
        g_kernel<false><<<grid_g, NTHREADS, 0, stream>>>(
            nullptr, nullptr, h0[1 - cur], h1[cur], rz1,
            Wg + W1, bg + HID, h1[1 - cur],
            h1_all + (size_t)t * BH);
        cur ^= 1;
    }

    final_h<<<(BH + 255) / 256, 256, 0, stream>>>(
        h0[cur], h1[cur], out + (size_t)T_STEPS * BATCH * VOCAB);

    dim3 grid_lg((VOCAB + TN - 1) / TN, (T_STEPS * BATCH) / TM);  // (157, 256)
    logits_kernel<<<grid_lg, NTHREADS, 0, stream>>>(h1_all, Wout, bout, out);
}

// Round 2
// 7891.475 us; speedup vs baseline: 7.8821x; 7.8821x over previous
//
#include <hip/hip_runtime.h>

#define T_STEPS 64
#define BATCH   128
#define HID     1024
#define VOCAB   10000
#define VPAD    10240

typedef unsigned short ushort_t;
typedef __attribute__((ext_vector_type(8))) short bf16x8_t;
typedef __attribute__((ext_vector_type(4))) float f32x4_t;

__device__ inline unsigned short f2bf(float f) {
    unsigned int u = __float_as_uint(f);
    u += 0x7fffu + ((u >> 16) & 1u);
    return (unsigned short)(u >> 16);
}

// ---------------------------------------------------------------------------
// init / final copies
// ---------------------------------------------------------------------------
__global__ void init_h(const float* __restrict__ hidden,
                       float* __restrict__ h0, float* __restrict__ h1)
{
    int i = blockIdx.x * blockDim.x + threadIdx.x;
    if (i < BATCH * HID) {
        h0[i] = hidden[i];
        h1[i] = hidden[BATCH * HID + i];
    }
}

__global__ void final_h(const float* __restrict__ h0, const float* __restrict__ h1,
                        float* __restrict__ out)
{
    int i = blockIdx.x * blockDim.x + threadIdx.x;
    if (i < BATCH * HID) {
        out[i] = h0[i];
        out[BATCH * HID + i] = h1[i];
    }
}

// ---------------------------------------------------------------------------
// Wout transpose + bf16 convert: WT[v][k] = bf16(Wout[k][v]); rows >= VOCAB = 0
// grid (VPAD/32, HID/32), 256 threads
// ---------------------------------------------------------------------------
__global__ __launch_bounds__(256)
void woutT_kernel(const float* __restrict__ Wout, ushort_t* __restrict__ WT)
{
    __shared__ float ld[32][33];
    const int v0 = blockIdx.x * 32, k0 = blockIdx.y * 32;
    const int r = threadIdx.x >> 3;         // 0..31
    const int c4 = (threadIdx.x & 7) * 4;   // 0..28
    // read Wout[k0+r][v0+c4..+3]
    #pragma unroll
    for (int q = 0; q < 4; ++q) {
        int v = v0 + c4 + q;
        float val = 0.0f;
        if (v < VOCAB) val = Wout[(size_t)(k0 + r) * VOCAB + v];
        ld[c4 + q][r] = val;   // ld[vloc][kloc]
    }
    __syncthreads();
    // write WT[(v0+r)][k0+c4..+3]
    ushort4 o;
    o.x = f2bf(ld[r][c4 + 0]);
    o.y = f2bf(ld[r][c4 + 1]);
    o.z = f2bf(ld[r][c4 + 2]);
    o.w = f2bf(ld[r][c4 + 3]);
    *(ushort4*)&WT[(size_t)(v0 + r) * HID + k0 + c4] = o;
}

// ---------------------------------------------------------------------------
// Precompute: xpre[i, j] = emb[ids[i]] @ Wsel[:,j]  for j in [0,3072)
//   j<1024 -> Wr0 top rows; j<2048 -> Wz0; else Wg0   (layer-0 top halves)
//   j<2048 -> xrz0[i][j]; else -> xg0[i][j-2048]
// TM=128, TN=32, TK=32, 256 threads, 4x4 per-thread tiles
// grid (3072/32=96, 8192/128=64)
// ---------------------------------------------------------------------------
__global__ __launch_bounds__(256)
void precompute_kernel(const int* __restrict__ ids, const float* __restrict__ emb,
                       const float* __restrict__ Wr, const float* __restrict__ Wz,
                       const float* __restrict__ Wg,
                       float* __restrict__ xrz0, float* __restrict__ xg0)
{
    __shared__ float As[32][132];
    __shared__ float Bs[32][36];
    const int tid = threadIdx.x;
    const int tx4 = (tid & 7) * 4;
    const int ty4 = (tid >> 3) * 4;
    const int j0v = blockIdx.x * 32;          // virtual col 0..3071
    const int i0 = blockIdx.y * 128;

    const float* W;
    int jc;
    if (j0v < 1024)      { W = Wr; jc = j0v; }
    else if (j0v < 2048) { W = Wz; jc = j0v - 1024; }
    else                 { W = Wg; jc = j0v - 2048; }

    float acc[4][4] = {};

    for (int kt = 0; kt < 1024; kt += 32) {
        // A stage (transposed): emb gather rows
        #pragma unroll
        for (int it = 0; it < 4; ++it) {
            int e4 = it * 256 + tid;
            int r = e4 >> 3;
            int kc = (e4 & 7) * 4;
            int row = ids[i0 + r];
            float4 v = *(const float4*)&emb[(size_t)row * HID + kt + kc];
            As[kc + 0][r] = v.x; As[kc + 1][r] = v.y;
            As[kc + 2][r] = v.z; As[kc + 3][r] = v.w;
        }
        // B stage
        {
            int kr = tid >> 3;
            int c = (tid & 7) * 4;
            *(float4*)&Bs[kr][c] =
                *(const float4*)&W[(size_t)(kt + kr) * HID + jc + c];
        }
        __syncthreads();
        #pragma unroll
        for (int kk = 0; kk < 32; ++kk) {
            float a[4], b[4];
            *(float4*)a = *(const float4*)&As[kk][ty4];
            *(float4*)b = *(const float4*)&Bs[kk][tx4];
            #pragma unroll
            for (int i = 0; i < 4; ++i)
                #pragma unroll
                for (int j = 0; j < 4; ++j)
                    acc[i][j] += a[i] * b[j];
        }
        __syncthreads();
    }

    #pragma unroll
    for (int i = 0; i < 4; ++i) {
        int row = i0 + ty4 + i;
        float4 v; v.x = acc[i][0]; v.y = acc[i][1]; v.z = acc[i][2]; v.w = acc[i][3];
        if (j0v < 2048)
            *(float4*)&xrz0[(size_t)row * 2048 + j0v + tx4] = v;
        else
            *(float4*)&xg0[(size_t)row * 1024 + (j0v - 2048) + tx4] = v;
    }
}

// ---------------------------------------------------------------------------
// Agemm: rz partial GEMMs, split-K (chunk 512), both layers pipelined.
//   layer0 (t=s):   A[b,k]=h0[b,k]          K=1024 (2 splits), wrow=1024+k
//   layer1 (t=s-1): A[b,k]=k<1024? h0 : h1  K=2048 (4 splits), wrow=k
//   B col j in [0,2048): j<1024 -> Wr else Wz (per-layer offset)
// part_rz[layer][split][b*2048+j] = partial
// grid (64, 4, 2), 256 threads
// ---------------------------------------------------------------------------
__global__ __launch_bounds__(256)
void agemm_kernel(const float* __restrict__ h0, const float* __restrict__ h1,
                  const float* __restrict__ Wr, const float* __restrict__ Wz,
                  float* __restrict__ part_rz, int do0, int do1)
{
    const int layer = blockIdx.z;
    const int split = blockIdx.y;
    if (layer == 0 && (!do0 || split >= 2)) return;
    if (layer == 1 && !do1) return;

    __shared__ float As[32][132];
    __shared__ float Bs[32][36];
    const int tid = threadIdx.x;
    const int tx4 = (tid & 7) * 4;
    const int ty4 = (tid >> 3) * 4;
    const int j0 = blockIdx.x * 32;
    const int kbase = split * 512;

    const float* W = ((j0 < 1024) ? Wr : Wz) + (size_t)layer * (2 * HID * HID);
    const int jc = j0 & (HID - 1);

    float acc[4][4] = {};

    for (int kt = 0; kt < 512; kt += 32) {
        #pragma unroll
        for (int it = 0; it < 4; ++it) {
            int e4 = it * 256 + tid;
            int r = e4 >> 3;
            int kc = (e4 & 7) * 4;
            int kg = kbase + kt + kc;
            float4 v;
            if (layer == 0) {
                v = *(const float4*)&h0[(size_t)r * HID + kg];
            } else {
                if (kg < HID) v = *(const float4*)&h0[(size_t)r * HID + kg];
                else          v = *(const float4*)&h1[(size_t)r * HID + kg - HID];
            }
            As[kc + 0][r] = v.x; As[kc + 1][r] = v.y;
            As[kc + 2][r] = v.z; As[kc + 3][r] = v.w;
        }
        {
            int kr = tid >> 3;
            int c = (tid & 7) * 4;
            int kg = kbase + kt + kr;
            int wrow = (layer == 0) ? (HID + kg) : kg;
            *(float4*)&Bs[kr][c] = *(const float4*)&W[(size_t)wrow * HID + jc + c];
        }
        __syncthreads();
        #pragma unroll
        for (int kk = 0; kk < 32; ++kk) {
            float a[4], b[4];
            *(float4*)a = *(const float4*)&As[kk][ty4];
            *(float4*)b = *(const float4*)&Bs[kk][tx4];
            #pragma unroll
            for (int i = 0; i < 4; ++i)
                #pragma unroll
                for (int j = 0; j < 4; ++j)
                    acc[i][j] += a[i] * b[j];
        }
        __syncthreads();
    }

    float* dst = part_rz + (size_t)(layer * 4 + split) * (BATCH * 2 * HID);
    #pragma unroll
    for (int i = 0; i < 4; ++i) {
        int b = ty4 + i;
        float4 v; v.x = acc[i][0]; v.y = acc[i][1]; v.z = acc[i][2]; v.w = acc[i][3];
        *(float4*)&dst[(size_t)b * 2048 + j0 + tx4] = v;
    }
}

// ---------------------------------------------------------------------------
// Aact: reduce rz partials + xpre + bias, tanh -> rzmat
// grid (1024, 2), 256 threads
// ---------------------------------------------------------------------------
__global__ __launch_bounds__(256)
void aact_kernel(const float* __restrict__ part_rz, const float* __restrict__ xrz0,
                 const float* __restrict__ br, const float* __restrict__ bz,
                 float* __restrict__ rzmat0, float* __restrict__ rzmat1,
                 int t0, int do0, int do1)
{
    const int layer = blockIdx.y;
    if (layer == 0 && !do0) return;
    if (layer == 1 && !do1) return;
    const int idx = blockIdx.x * 256 + threadIdx.x;   // 0..262143
    const int b = idx >> 11, j = idx & 2047;
    const float* p = part_rz + (size_t)layer * 4 * (BATCH * 2 * HID);
    const int N = BATCH * 2 * HID;
    float s = p[idx] + p[N + idx];
    if (layer == 0) s += xrz0[((size_t)t0 * BATCH + b) * 2048 + j];
    else            s += p[2 * N + idx] + p[3 * N + idx];
    float bias = (j < HID) ? br[layer * HID + j] : bz[layer * HID + (j - HID)];
    float v = tanhf(s + bias);
    (layer == 0 ? rzmat0 : rzmat1)[idx] = v;
}

// ---------------------------------------------------------------------------
// Bgemm: g partial GEMMs, split-K, both layers.
//   layer0: A[b,k] = r0[b,k]*h0[b,k]            K=1024 (2 splits), wrow=1024+k
//   layer1: A[b,k] = k<1024? h0 : r1*h1          K=2048 (4 splits), wrow=k
// grid (32, 4, 2), 256 threads
// ---------------------------------------------------------------------------
__global__ __launch_bounds__(256)
void bgemm_kernel(const float* __restrict__ h0, const float* __restrict__ h1,
                  const float* __restrict__ rzmat0, const float* __restrict__ rzmat1,
                  const float* __restrict__ Wg,
                  float* __restrict__ part_g, int do0, int do1)
{
    const int layer = blockIdx.z;
    const int split = blockIdx.y;
    if (layer == 0 && (!do0 || split >= 2)) return;
    if (layer == 1 && !do1) return;

    __shared__ float As[32][132];
    __shared__ float Bs[32][36];
    const int tid = threadIdx.x;
    const int tx4 = (tid & 7) * 4;
    const int ty4 = (tid >> 3) * 4;
    const int j0 = blockIdx.x * 32;
    const int kbase = split * 512;

    const float* W = Wg + (size_t)layer * (2 * HID * HID);

    float acc[4][4] = {};

    for (int kt = 0; kt < 512; kt += 32) {
        #pragma unroll
        for (int it = 0; it < 4; ++it) {
            int e4 = it * 256 + tid;
            int r = e4 >> 3;
            int kc = (e4 & 7) * 4;
            int kg = kbase + kt + kc;
            float4 v;
            if (layer == 0) {
                float4 rv = *(const float4*)&rzmat0[(size_t)r * 2048 + kg];
                float4 hv = *(const float4*)&h0[(size_t)r * HID + kg];
                v.x = rv.x * hv.x; v.y = rv.y * hv.y; v.z = rv.z * hv.z; v.w = rv.w * hv.w;
            } else {
                if (kg < HID) {
                    v = *(const float4*)&h0[(size_t)r * HID + kg];
                } else {
                    float4 rv = *(const float4*)&rzmat1[(size_t)r * 2048 + (kg - HID)];
                    float4 hv = *(const float4*)&h1[(size_t)r * HID + (kg - HID)];
                    v.x = rv.x * hv.x; v.y = rv.y * hv.y; v.z = rv.z * hv.z; v.w = rv.w * hv.w;
                }
            }
            As[kc + 0][r] = v.x; As[kc + 1][r] = v.y;
            As[kc + 2][r] = v.z; As[kc + 3][r] = v.w;
        }
        {
            int kr = tid >> 3;
            int c = (tid & 7) * 4;
            int kg = kbase + kt + kr;
            int wrow = (layer == 0) ? (HID + kg) : kg;
            *(float4*)&Bs[kr][c] = *(const float4*)&W[(size_t)wrow * HID + j0 + c];
        }
        __syncthreads();
        #pragma unroll
        for (int kk = 0; kk < 32; ++kk) {
            float a[4], b[4];
            *(float4*)a = *(const float4*)&As[kk][ty4];
            *(float4*)b = *(const float4*)&Bs[kk][tx4];
            #pragma unroll
            for (int i = 0; i < 4; ++i)
                #pragma unroll
                for (int j = 0; j < 4; ++j)
                    acc[i][j] += a[i] * b[j];
        }
        __syncthreads();
    }

    float* dst = part_g + (size_t)(layer * 4 + split) * (BATCH * HID);
    #pragma unroll
    for (int i = 0; i < 4; ++i) {
        int b = ty4 + i;
        float4 v; v.x = acc[i][0]; v.y = acc[i][1]; v.z = acc[i][2]; v.w = acc[i][3];
        *(float4*)&dst[(size_t)b * HID + j0 + tx4] = v;
    }
}

// ---------------------------------------------------------------------------
// Bact: reduce g partials + bias (+xg0 for layer0), tanh, h update (in-place)
// layer1 also writes h1bf[t1] (bf16 for logits GEMM)
// grid (512, 2), 256 threads
// ---------------------------------------------------------------------------
__global__ __launch_bounds__(256)
void bact_kernel(const float* __restrict__ part_g, const float* __restrict__ xg0,
                 const float* __restrict__ bg,
                 const float* __restrict__ rzmat0, const float* __restrict__ rzmat1,
                 float* __restrict__ h0, float* __restrict__ h1,
                 ushort_t* __restrict__ h1bf, int t0, int t1, int do0, int do1)
{
    const int layer = blockIdx.y;
    if (layer == 0 && !do0) return;
    if (layer == 1 && !do1) return;
    const int idx = blockIdx.x * 256 + threadIdx.x;    // 0..131071
    const int b = idx >> 10, j = idx & 1023;
    const float* p = part_g + (size_t)layer * 4 * (BATCH * HID);
    const int N = BATCH * HID;
    float s = p[idx] + p[N + idx];
    if (layer == 0) s += xg0[((size_t)t0 * BATCH + b) * 1024 + j];
    else            s += p[2 * N + idx] + p[3 * N + idx];
    float ht = tanhf(s + bg[layer * HID + j]);
    if (layer == 0) {
        float z = rzmat0[(size_t)b * 2048 + HID + j];
        h0[idx] = (1.0f - z) * h0[idx] + z * ht;
    } else {
        float z = rzmat1[(size_t)b * 2048 + HID + j];
        float hn = (1.0f - z) * h1[idx] + z * ht;
        h1[idx] = hn;
        h1bf[(size_t)t1 * (BATCH * HID) + idx] = f2bf(hn);
    }
}

// ---------------------------------------------------------------------------
// Logits MFMA GEMM: out[i,v] = tanh(h1bf[i,:] @ WT[v,:] + bout[v])
// M=8192, N=VPAD(store guarded to VOCAB), K=1024. bf16 inputs, f32 out.
// 128x128 tile, BK=64, 4 waves, global_load_lds(16B) with source-side swizzle.
// grid (VPAD/128=80, 8192/128=64), 256 threads
// ---------------------------------------------------------------------------
typedef const unsigned int __attribute__((address_space(1)))* gptr1_t;
typedef unsigned int __attribute__((address_space(3)))* lptr3_t;

__global__ __launch_bounds__(256)
void logits_mfma_kernel(const ushort_t* __restrict__ Abf,
                        const ushort_t* __restrict__ BT,
                        const float* __restrict__ bout,
                        float* __restrict__ out)
{
    __shared__ ushort_t As[128 * 64];
    __shared__ ushort_t Bs[128 * 64];
    const int tid = threadIdx.x;
    const int wave = tid >> 6, lane = tid & 63;
    const int m0 = blockIdx.y * 128, n0 = blockIdx.x * 128;
    const int wr = wave >> 1, wc = wave & 1;

    const int srow = lane >> 3;                       // 0..7
    const int sch = (lane & 7) ^ (srow & 7);          // pre-swizzled src chunk
    const int lrow = lane & 15, lhi = lane >> 4;

    f32x4_t acc[4][4] = {};

    for (int k0 = 0; k0 < HID; k0 += 64) {
        // stage A and B tiles (each wave: 4 issues of 8 rows x 64 bf16)
        #pragma unroll
        for (int i = 0; i < 4; ++i) {
            int issue = wave * 4 + i;
            int row = issue * 8 + srow;
            const ushort_t* ga = Abf + (size_t)(m0 + row) * HID + k0 + sch * 8;
            const ushort_t* gb = BT + (size_t)(n0 + row) * HID + k0 + sch * 8;
#if defined(__has_builtin) && __has_builtin(__builtin_amdgcn_global_load_lds)
            __builtin_amdgcn_global_load_lds((gptr1_t)(const void*)ga,
                                             (lptr3_t)(void*)(As + issue * 512), 16, 0, 0);
            __builtin_amdgcn_global_load_lds((gptr1_t)(const void*)gb,
                                             (lptr3_t)(void*)(Bs + issue * 512), 16, 0, 0);
#else
            *(bf16x8_t*)(As + issue * 512 + lane * 8) = *(const bf16x8_t*)ga;
            *(bf16x8_t*)(Bs + issue * 512 + lane * 8) = *(const bf16x8_t*)gb;
#endif
        }
        __syncthreads();

        bf16x8_t af[4][2], bf[4][2];
        const char* Ab = (const char*)As;
        const char* Bb = (const char*)Bs;
        #pragma unroll
        for (int m = 0; m < 4; ++m) {
            int row = wr * 64 + m * 16 + lrow;
            #pragma unroll
            for (int ks = 0; ks < 2; ++ks) {
                int off = row * 128 + (((ks * 4 + lhi) ^ (lrow & 7)) * 16);
                af[m][ks] = *(const bf16x8_t*)(Ab + off);
            }
        }
        #pragma unroll
        for (int n = 0; n < 4; ++n) {
            int row = wc * 64 + n * 16 + lrow;
            #pragma unroll
            for (int ks = 0; ks < 2; ++ks) {
                int off = row * 128 + (((ks * 4 + lhi) ^ (lrow & 7)) * 16);
                bf[n][ks] = *(const bf16x8_t*)(Bb + off);
            }
        }
        #pragma unroll
        for (int m = 0; m < 4; ++m)
            #pragma unroll
            for (int n = 0; n < 4; ++n)
                #pragma unroll
                for (int ks = 0; ks < 2; ++ks)
                    acc[m][n] = __builtin_amdgcn_mfma_f32_16x16x32_bf16(
                        af[m][ks], bf[n][ks], acc[m][n], 0, 0, 0);
        __syncthreads();
    }

    #pragma unroll
    for (int m = 0; m < 4; ++m) {
        int row = m0 + wr * 64 + m * 16 + lhi * 4;
        #pragma unroll
        for (int n = 0; n < 4; ++n) {
            int col = n0 + wc * 64 + n * 16 + lrow;
            if (col < VOCAB) {
                float bo = bout[col];
                #pragma unroll
                for (int q = 0; q < 4; ++q)
                    out[(size_t)(row + q) * VOCAB + col] = tanhf(acc[m][n][q] + bo);
            }
        }
    }
}

// ---------------------------------------------------------------------------
extern "C" void kernel_launch(void* const* d_in, const int* in_sizes, int n_in,
                              void* d_out, int out_size, void* d_ws, size_t ws_size,
                              hipStream_t stream)
{
    const int*   inputs = (const int*)  d_in[0];
    const float* hidden = (const float*)d_in[1];
    const float* emb    = (const float*)d_in[2];
    const float* Wr     = (const float*)d_in[3];
    const float* br     = (const float*)d_in[4];
    const float* Wz     = (const float*)d_in[5];
    const float* bz     = (const float*)d_in[6];
    const float* Wg     = (const float*)d_in[7];
    const float* bg     = (const float*)d_in[8];
    const float* Wout   = (const float*)d_in[9];
    const float* bout   = (const float*)d_in[10];
    float* out = (float*)d_out;

    const size_t BH = BATCH * HID;          // 131072

    float* ws = (float*)d_ws;
    float* h0      = ws;                     // BH
    float* h1      = h0 + BH;                // BH
    float* rzmat0  = h1 + BH;                // 262144
    float* rzmat1  = rzmat0 + 262144;        // 262144
    float* part_rz = rzmat1 + 262144;        // 2 x 4 x 262144 = 2097152
    float* part_g  = part_rz + 2097152;      // 2 x 4 x 131072 = 1048576
    float* xrz0    = part_g + 1048576;       // 8192 x 2048 = 16777216
    float* xg0     = xrz0 + 16777216;        // 8192 x 1024 = 8388608
    ushort_t* h1bf = (ushort_t*)(xg0 + 8388608);            // T*B*H bf16
    ushort_t* WT   = (ushort_t*)(xg0 + 8388608 + 4194304);  // VPAD*H bf16

    init_h<<<(int)(BH + 255) / 256, 256, 0, stream>>>(hidden, h0, h1);

    woutT_kernel<<<dim3(VPAD / 32, HID / 32), 256, 0, stream>>>(Wout, WT);

    precompute_kernel<<<dim3(96, 64), 256, 0, stream>>>(
        inputs, emb, Wr, Wz, Wg, xrz0, xg0);

    for (int s = 0; s <= T_STEPS; ++s) {
        int do0 = (s < T_STEPS) ? 1 : 0;
        int do1 = (s >= 1) ? 1 : 0;
        int t0 = s, t1 = s - 1;
        agemm_kernel<<<dim3(64, 4, 2), 256, 0, stream>>>(
            h0, h1, Wr, Wz, part_rz, do0, do1);
        aact_kernel<<<dim3(1024, 2), 256, 0, stream>>>(
            part_rz, xrz0, br, bz, rzmat0, rzmat1, t0, do0, do1);
        bgemm_kernel<<<dim3(32, 4, 2), 256, 0, stream>>>(
            h0, h1, rzmat0, rzmat1, Wg, part_g, do0, do1);
        bact_kernel<<<dim3(512, 2), 256, 0, stream>>>(
            part_g, xg0, bg, rzmat0, rzmat1, h0, h1, h1bf, t0, t1, do0, do1);
    }

    final_h<<<(int)(BH + 255) / 256, 256, 0, stream>>>(
        h0, h1, out + (size_t)T_STEPS * BATCH * VOCAB);

    logits_mfma_kernel<<<dim3(VPAD / 128, 8192 / 128), 256, 0, stream>>>(
        h1bf, WT, bout, out);
}

// Round 3
// 5011.782 us; speedup vs baseline: 12.4110x; 1.5746x over previous
//
#include <hip/hip_runtime.h>

#define T_STEPS 64
#define BATCH   128
#define HID     1024
#define VOCAB   10000
#define VPAD    10240
#define NSPLIT  8
#define KCHUNK  256
#define TKK     64

typedef unsigned short ushort_t;
typedef __attribute__((ext_vector_type(8))) short bf16x8_t;
typedef __attribute__((ext_vector_type(4))) float f32x4_t;

__device__ inline unsigned short f2bf(float f) {
    unsigned int u = __float_as_uint(f);
    u += 0x7fffu + ((u >> 16) & 1u);
    return (unsigned short)(u >> 16);
}

// ---------------------------------------------------------------------------
// init / final copies
// ---------------------------------------------------------------------------
__global__ void init_h(const float* __restrict__ hidden,
                       float* __restrict__ h0, float* __restrict__ h1)
{
    int i = blockIdx.x * blockDim.x + threadIdx.x;
    if (i < BATCH * HID) {
        h0[i] = hidden[i];
        h1[i] = hidden[BATCH * HID + i];
    }
}

__global__ void final_h(const float* __restrict__ h0, const float* __restrict__ h1,
                        float* __restrict__ out)
{
    int i = blockIdx.x * blockDim.x + threadIdx.x;
    if (i < BATCH * HID) {
        out[i] = h0[i];
        out[BATCH * HID + i] = h1[i];
    }
}

// ---------------------------------------------------------------------------
// Embedding gather: xemb[row][k] = emb[ids[row]][k], row in [0, T*B)
// grid (T*B = 8192), 256 threads (one float4 per thread)
// ---------------------------------------------------------------------------
__global__ __launch_bounds__(256)
void gather_kernel(const int* __restrict__ ids, const float* __restrict__ emb,
                   float* __restrict__ xemb)
{
    const int row = blockIdx.x;
    const int c4 = threadIdx.x * 4;
    float4 v = *(const float4*)&emb[(size_t)ids[row] * HID + c4];
    *(float4*)&xemb[(size_t)row * HID + c4] = v;
}

// ---------------------------------------------------------------------------
// Wout transpose + bf16 convert: WT[v][k] = bf16(Wout[k][v]); rows >= VOCAB = 0
// grid (VPAD/32, HID/32), 256 threads
// ---------------------------------------------------------------------------
__global__ __launch_bounds__(256)
void woutT_kernel(const float* __restrict__ Wout, ushort_t* __restrict__ WT)
{
    __shared__ float ld[32][33];
    const int v0 = blockIdx.x * 32, k0 = blockIdx.y * 32;
    const int r = threadIdx.x >> 3;
    const int c4 = (threadIdx.x & 7) * 4;
    #pragma unroll
    for (int q = 0; q < 4; ++q) {
        int v = v0 + c4 + q;
        float val = 0.0f;
        if (v < VOCAB) val = Wout[(size_t)(k0 + r) * VOCAB + v];
        ld[c4 + q][r] = val;
    }
    __syncthreads();
    ushort4 o;
    o.x = f2bf(ld[r][c4 + 0]);
    o.y = f2bf(ld[r][c4 + 1]);
    o.z = f2bf(ld[r][c4 + 2]);
    o.w = f2bf(ld[r][c4 + 3]);
    *(ushort4*)&WT[(size_t)(v0 + r) * HID + k0 + c4] = o;
}

// ---------------------------------------------------------------------------
// agemm: rz partial GEMMs, split-K chunk 256, 8 splits, both layers.
//   A[b,k] (layer0) = k<H ? xemb_t0[b,k] : h0[b,k-H]   (K=2048)
//   A[b,k] (layer1) = k<H ? h0[b,k]      : h1[b,k-H]   (K=2048)
//   B col j in [0,2048): j<H -> Wr[k,:] else Wz[k,:]
// part_rz[layer][split][b*2048+j] = partial
// grid (64, 8, 2), 256 threads, TM=128/TN=32/TK=64, 4x4 per-thread tiles
// ---------------------------------------------------------------------------
__global__ __launch_bounds__(256)
void agemm_kernel(const float* __restrict__ xemb_t0,
                  const float* __restrict__ h0, const float* __restrict__ h1,
                  const float* __restrict__ Wr, const float* __restrict__ Wz,
                  float* __restrict__ part_rz, int do0, int do1)
{
    const int layer = blockIdx.z;
    if (layer == 0 && !do0) return;
    if (layer == 1 && !do1) return;

    __shared__ float As[TKK][132];
    __shared__ float Bs[TKK][36];
    const int tid = threadIdx.x;
    const int tx4 = (tid & 7) * 4;
    const int ty4 = (tid >> 3) * 4;
    const int j0 = blockIdx.x * 32;
    const int kbase = blockIdx.y * KCHUNK;

    const float* W = ((j0 < HID) ? Wr : Wz) + (size_t)layer * (2 * HID * HID);
    const int jc = j0 & (HID - 1);
    const float* A_lo = layer ? h0 : xemb_t0;
    const float* A_hi = layer ? h1 : h0;

    float acc[4][4] = {};

    for (int kt = 0; kt < KCHUNK; kt += TKK) {
        // stage A (transposed): [TKK kk][128 b], 8 float4 per thread
        #pragma unroll
        for (int i = 0; i < 8; ++i) {
            int e = (i & 3) * 256 + tid;
            int r = e >> 3;
            int kc = (e & 7) * 4 + (i >> 2) * 32;
            int kg = kbase + kt + kc;
            const float* src = (kg < HID) ? A_lo : A_hi;
            float4 v = *(const float4*)&src[(size_t)r * HID + (kg & (HID - 1))];
            As[kc + 0][r] = v.x; As[kc + 1][r] = v.y;
            As[kc + 2][r] = v.z; As[kc + 3][r] = v.w;
        }
        // stage B: [TKK][32], 2 float4 per thread
        #pragma unroll
        for (int i = 0; i < 2; ++i) {
            int e = i * 256 + tid;
            int kr = e >> 3;
            int c = (e & 7) * 4;
            *(float4*)&Bs[kr][c] =
                *(const float4*)&W[(size_t)(kbase + kt + kr) * HID + jc + c];
        }
        __syncthreads();
        #pragma unroll
        for (int kk = 0; kk < TKK; ++kk) {
            float a[4], b[4];
            *(float4*)a = *(const float4*)&As[kk][ty4];
            *(float4*)b = *(const float4*)&Bs[kk][tx4];
            #pragma unroll
            for (int i = 0; i < 4; ++i)
                #pragma unroll
                for (int j = 0; j < 4; ++j)
                    acc[i][j] += a[i] * b[j];
        }
        __syncthreads();
    }

    float* dst = part_rz + (size_t)(layer * NSPLIT + blockIdx.y) * (BATCH * 2 * HID);
    #pragma unroll
    for (int i = 0; i < 4; ++i) {
        int b = ty4 + i;
        float4 v; v.x = acc[i][0]; v.y = acc[i][1]; v.z = acc[i][2]; v.w = acc[i][3];
        *(float4*)&dst[(size_t)b * 2048 + j0 + tx4] = v;
    }
}

// ---------------------------------------------------------------------------
// aact: r only. r = tanh(sum_splits part_rz[.., j<H] + br)
// grid (128, 2), 256 threads, float4 per thread
// ---------------------------------------------------------------------------
__global__ __launch_bounds__(256)
void aact_kernel(const float* __restrict__ part_rz,
                 const float* __restrict__ br,
                 float* __restrict__ rmat0, float* __restrict__ rmat1,
                 int do0, int do1)
{
    const int layer = blockIdx.y;
    if (layer == 0 && !do0) return;
    if (layer == 1 && !do1) return;
    const int idx4 = (blockIdx.x * 256 + threadIdx.x) * 4;   // [0, 131072)
    const int b = idx4 >> 10, j = idx4 & (HID - 1);
    const float* p = part_rz + (size_t)layer * NSPLIT * (BATCH * 2 * HID)
                   + (size_t)b * 2048 + j;
    float4 s = {0.f, 0.f, 0.f, 0.f};
    #pragma unroll
    for (int sp = 0; sp < NSPLIT; ++sp) {
        float4 v = *(const float4*)&p[(size_t)sp * (BATCH * 2 * HID)];
        s.x += v.x; s.y += v.y; s.z += v.z; s.w += v.w;
    }
    float4 bb = *(const float4*)&br[layer * HID + j];
    float4 r;
    r.x = tanhf(s.x + bb.x); r.y = tanhf(s.y + bb.y);
    r.z = tanhf(s.z + bb.z); r.w = tanhf(s.w + bb.w);
    *(float4*)&(layer ? rmat1 : rmat0)[idx4] = r;
}

// ---------------------------------------------------------------------------
// bgemm: g partial GEMMs, split-K chunk 256, 8 splits, both layers. K=2048.
//   A2[b,k] (layer0) = k<H ? xemb_t0[b,k] : r0[b,k-H]*h0[b,k-H]
//   A2[b,k] (layer1) = k<H ? h0[b,k]      : r1[b,k-H]*h1[b,k-H]
// grid (32, 8, 2), 256 threads
// ---------------------------------------------------------------------------
__global__ __launch_bounds__(256)
void bgemm_kernel(const float* __restrict__ xemb_t0,
                  const float* __restrict__ h0, const float* __restrict__ h1,
                  const float* __restrict__ rmat0, const float* __restrict__ rmat1,
                  const float* __restrict__ Wg,
                  float* __restrict__ part_g, int do0, int do1)
{
    const int layer = blockIdx.z;
    if (layer == 0 && !do0) return;
    if (layer == 1 && !do1) return;

    __shared__ float As[TKK][132];
    __shared__ float Bs[TKK][36];
    const int tid = threadIdx.x;
    const int tx4 = (tid & 7) * 4;
    const int ty4 = (tid >> 3) * 4;
    const int j0 = blockIdx.x * 32;
    const int kbase = blockIdx.y * KCHUNK;

    const float* W = Wg + (size_t)layer * (2 * HID * HID);
    const float* A_lo = layer ? h0 : xemb_t0;
    const float* A_hi = layer ? h1 : h0;
    const float* R    = layer ? rmat1 : rmat0;

    float acc[4][4] = {};

    for (int kt = 0; kt < KCHUNK; kt += TKK) {
        #pragma unroll
        for (int i = 0; i < 8; ++i) {
            int e = (i & 3) * 256 + tid;
            int r = e >> 3;
            int kc = (e & 7) * 4 + (i >> 2) * 32;
            int kg = kbase + kt + kc;
            int km = kg & (HID - 1);
            float4 v;
            if (kg < HID) {
                v = *(const float4*)&A_lo[(size_t)r * HID + km];
            } else {
                float4 rv = *(const float4*)&R[(size_t)r * HID + km];
                float4 hv = *(const float4*)&A_hi[(size_t)r * HID + km];
                v.x = rv.x * hv.x; v.y = rv.y * hv.y;
                v.z = rv.z * hv.z; v.w = rv.w * hv.w;
            }
            As[kc + 0][r] = v.x; As[kc + 1][r] = v.y;
            As[kc + 2][r] = v.z; As[kc + 3][r] = v.w;
        }
        #pragma unroll
        for (int i = 0; i < 2; ++i) {
            int e = i * 256 + tid;
            int kr = e >> 3;
            int c = (e & 7) * 4;
            *(float4*)&Bs[kr][c] =
                *(const float4*)&W[(size_t)(kbase + kt + kr) * HID + j0 + c];
        }
        __syncthreads();
        #pragma unroll
        for (int kk = 0; kk < TKK; ++kk) {
            float a[4], b[4];
            *(float4*)a = *(const float4*)&As[kk][ty4];
            *(float4*)b = *(const float4*)&Bs[kk][tx4];
            #pragma unroll
            for (int i = 0; i < 4; ++i)
                #pragma unroll
                for (int j = 0; j < 4; ++j)
                    acc[i][j] += a[i] * b[j];
        }
        __syncthreads();
    }

    float* dst = part_g + (size_t)(layer * NSPLIT + blockIdx.y) * (BATCH * HID);
    #pragma unroll
    for (int i = 0; i < 4; ++i) {
        int b = ty4 + i;
        float4 v; v.x = acc[i][0]; v.y = acc[i][1]; v.z = acc[i][2]; v.w = acc[i][3];
        *(float4*)&dst[(size_t)b * HID + j0 + tx4] = v;
    }
}

// ---------------------------------------------------------------------------
// bact: z = tanh(sum part_rz[.., H+j] + bz); g~ = tanh(sum part_g + bg);
//       h = (1-z)*h + z*g~; layer1 also writes h1bf[t1] (bf16)
// grid (128, 2), 256 threads, float4 per thread
// ---------------------------------------------------------------------------
__global__ __launch_bounds__(256)
void bact_kernel(const float* __restrict__ part_rz, const float* __restrict__ part_g,
                 const float* __restrict__ bz, const float* __restrict__ bg,
                 float* __restrict__ h0, float* __restrict__ h1,
                 ushort_t* __restrict__ h1bf, int t1, int do0, int do1)
{
    const int layer = blockIdx.y;
    if (layer == 0 && !do0) return;
    if (layer == 1 && !do1) return;
    const int idx4 = (blockIdx.x * 256 + threadIdx.x) * 4;   // [0, 131072)
    const int b = idx4 >> 10, j = idx4 & (HID - 1);

    const float* pz = part_rz + (size_t)layer * NSPLIT * (BATCH * 2 * HID)
                    + (size_t)b * 2048 + HID + j;
    float4 sz = {0.f, 0.f, 0.f, 0.f};
    #pragma unroll
    for (int sp = 0; sp < NSPLIT; ++sp) {
        float4 v = *(const float4*)&pz[(size_t)sp * (BATCH * 2 * HID)];
        sz.x += v.x; sz.y += v.y; sz.z += v.z; sz.w += v.w;
    }
    float4 bzv = *(const float4*)&bz[layer * HID + j];
    float4 z;
    z.x = tanhf(sz.x + bzv.x); z.y = tanhf(sz.y + bzv.y);
    z.z = tanhf(sz.z + bzv.z); z.w = tanhf(sz.w + bzv.w);

    const float* pg = part_g + (size_t)layer * NSPLIT * (BATCH * HID) + idx4;
    float4 sg = {0.f, 0.f, 0.f, 0.f};
    #pragma unroll
    for (int sp = 0; sp < NSPLIT; ++sp) {
        float4 v = *(const float4*)&pg[(size_t)sp * (BATCH * HID)];
        sg.x += v.x; sg.y += v.y; sg.z += v.z; sg.w += v.w;
    }
    float4 bgv = *(const float4*)&bg[layer * HID + j];
    float4 g;
    g.x = tanhf(sg.x + bgv.x); g.y = tanhf(sg.y + bgv.y);
    g.z = tanhf(sg.z + bgv.z); g.w = tanhf(sg.w + bgv.w);

    float* h = layer ? h1 : h0;
    float4 hv = *(const float4*)&h[idx4];
    float4 hn;
    hn.x = (1.0f - z.x) * hv.x + z.x * g.x;
    hn.y = (1.0f - z.y) * hv.y + z.y * g.y;
    hn.z = (1.0f - z.z) * hv.z + z.z * g.z;
    hn.w = (1.0f - z.w) * hv.w + z.w * g.w;
    *(float4*)&h[idx4] = hn;

    if (layer == 1) {
        ushort4 o;
        o.x = f2bf(hn.x); o.y = f2bf(hn.y); o.z = f2bf(hn.z); o.w = f2bf(hn.w);
        *(ushort4*)&h1bf[(size_t)t1 * (BATCH * HID) + idx4] = o;
    }
}

// ---------------------------------------------------------------------------
// Logits MFMA GEMM: out[i,v] = tanh(h1bf[i,:] @ WT[v,:] + bout[v])
// M=8192, N=VPAD (store guarded to VOCAB), K=1024. bf16 in, f32 out.
// 128x128 tile, BK=64, 4 waves, global_load_lds(16B) with source-side swizzle.
// grid (VPAD/128=80, 8192/128=64), 256 threads
// ---------------------------------------------------------------------------
typedef const unsigned int __attribute__((address_space(1)))* gptr1_t;
typedef unsigned int __attribute__((address_space(3)))* lptr3_t;

__global__ __launch_bounds__(256)
void logits_mfma_kernel(const ushort_t* __restrict__ Abf,
                        const ushort_t* __restrict__ BT,
                        const float* __restrict__ bout,
                        float* __restrict__ out)
{
    __shared__ ushort_t As[128 * 64];
    __shared__ ushort_t Bs[128 * 64];
    const int tid = threadIdx.x;
    const int wave = tid >> 6, lane = tid & 63;
    const int m0 = blockIdx.y * 128, n0 = blockIdx.x * 128;
    const int wr = wave >> 1, wc = wave & 1;

    const int srow = lane >> 3;
    const int sch = (lane & 7) ^ (srow & 7);
    const int lrow = lane & 15, lhi = lane >> 4;

    f32x4_t acc[4][4] = {};

    for (int k0 = 0; k0 < HID; k0 += 64) {
        #pragma unroll
        for (int i = 0; i < 4; ++i) {
            int issue = wave * 4 + i;
            int row = issue * 8 + srow;
            const ushort_t* ga = Abf + (size_t)(m0 + row) * HID + k0 + sch * 8;
            const ushort_t* gb = BT + (size_t)(n0 + row) * HID + k0 + sch * 8;
#if defined(__has_builtin) && __has_builtin(__builtin_amdgcn_global_load_lds)
            __builtin_amdgcn_global_load_lds((gptr1_t)(const void*)ga,
                                             (lptr3_t)(void*)(As + issue * 512), 16, 0, 0);
            __builtin_amdgcn_global_load_lds((gptr1_t)(const void*)gb,
                                             (lptr3_t)(void*)(Bs + issue * 512), 16, 0, 0);
#else
            *(bf16x8_t*)(As + issue * 512 + lane * 8) = *(const bf16x8_t*)ga;
            *(bf16x8_t*)(Bs + issue * 512 + lane * 8) = *(const bf16x8_t*)gb;
#endif
        }
        __syncthreads();

        bf16x8_t af[4][2], bfm[4][2];
        const char* Ab = (const char*)As;
        const char* Bb = (const char*)Bs;
        #pragma unroll
        for (int m = 0; m < 4; ++m) {
            int row = wr * 64 + m * 16 + lrow;
            #pragma unroll
            for (int ks = 0; ks < 2; ++ks) {
                int off = row * 128 + (((ks * 4 + lhi) ^ (lrow & 7)) * 16);
                af[m][ks] = *(const bf16x8_t*)(Ab + off);
            }
        }
        #pragma unroll
        for (int n = 0; n < 4; ++n) {
            int row = wc * 64 + n * 16 + lrow;
            #pragma unroll
            for (int ks = 0; ks < 2; ++ks) {
                int off = row * 128 + (((ks * 4 + lhi) ^ (lrow & 7)) * 16);
                bfm[n][ks] = *(const bf16x8_t*)(Bb + off);
            }
        }
        #pragma unroll
        for (int m = 0; m < 4; ++m)
            #pragma unroll
            for (int n = 0; n < 4; ++n)
                #pragma unroll
                for (int ks = 0; ks < 2; ++ks)
                    acc[m][n] = __builtin_amdgcn_mfma_f32_16x16x32_bf16(
                        af[m][ks], bfm[n][ks], acc[m][n], 0, 0, 0);
        __syncthreads();
    }

    #pragma unroll
    for (int m = 0; m < 4; ++m) {
        int row = m0 + wr * 64 + m * 16 + lhi * 4;
        #pragma unroll
        for (int n = 0; n < 4; ++n) {
            int col = n0 + wc * 64 + n * 16 + lrow;
            if (col < VOCAB) {
                float bo = bout[col];
                #pragma unroll
                for (int q = 0; q < 4; ++q)
                    out[(size_t)(row + q) * VOCAB + col] = tanhf(acc[m][n][q] + bo);
            }
        }
    }
}

// ---------------------------------------------------------------------------
extern "C" void kernel_launch(void* const* d_in, const int* in_sizes, int n_in,
                              void* d_out, int out_size, void* d_ws, size_t ws_size,
                              hipStream_t stream)
{
    const int*   inputs = (const int*)  d_in[0];
    const float* hidden = (const float*)d_in[1];
    const float* emb    = (const float*)d_in[2];
    const float* Wr     = (const float*)d_in[3];
    const float* br     = (const float*)d_in[4];
    const float* Wz     = (const float*)d_in[5];
    const float* bz     = (const float*)d_in[6];
    const float* Wg     = (const float*)d_in[7];
    const float* bg     = (const float*)d_in[8];
    const float* Wout   = (const float*)d_in[9];
    const float* bout   = (const float*)d_in[10];
    float* out = (float*)d_out;

    const size_t BH = BATCH * HID;                 // 131072

    float* ws = (float*)d_ws;
    float* h0      = ws;                           // BH
    float* h1      = h0 + BH;                      // BH
    float* rmat0   = h1 + BH;                      // BH
    float* rmat1   = rmat0 + BH;                   // BH
    float* part_rz = rmat1 + BH;                   // 2*8*262144 = 4194304
    float* part_g  = part_rz + 2 * NSPLIT * (BATCH * 2 * HID);  // 2*8*131072 = 2097152
    float* xemb    = part_g + 2 * NSPLIT * (BATCH * HID);       // T*B*H = 8388608
    ushort_t* h1bf = (ushort_t*)(xemb + (size_t)T_STEPS * BH);  // T*B*H bf16
    ushort_t* WT   = h1bf + (size_t)T_STEPS * BH;               // VPAD*H bf16

    init_h<<<(int)(BH + 255) / 256, 256, 0, stream>>>(hidden, h0, h1);
    gather_kernel<<<T_STEPS * BATCH, 256, 0, stream>>>(inputs, emb, xemb);
    woutT_kernel<<<dim3(VPAD / 32, HID / 32), 256, 0, stream>>>(Wout, WT);

    for (int s = 0; s <= T_STEPS; ++s) {
        int do0 = (s < T_STEPS) ? 1 : 0;
        int do1 = (s >= 1) ? 1 : 0;
        const float* xemb_t0 = xemb + (size_t)s * BH;
        agemm_kernel<<<dim3(64, NSPLIT, 2), 256, 0, stream>>>(
            xemb_t0, h0, h1, Wr, Wz, part_rz, do0, do1);
        aact_kernel<<<dim3(128, 2), 256, 0, stream>>>(
            part_rz, br, rmat0, rmat1, do0, do1);
        bgemm_kernel<<<dim3(32, NSPLIT, 2), 256, 0, stream>>>(
            xemb_t0, h0, h1, rmat0, rmat1, Wg, part_g, do0, do1);
        bact_kernel<<<dim3(128, 2), 256, 0, stream>>>(
            part_rz, part_g, bz, bg, h0, h1, h1bf, s - 1, do0, do1);
    }

    final_h<<<(int)(BH + 255) / 256, 256, 0, stream>>>(
        h0, h1, out + (size_t)T_STEPS * BATCH * VOCAB);

    logits_mfma_kernel<<<dim3(VPAD / 128, 8192 / 128), 256, 0, stream>>>(
        h1bf, WT, bout, out);
}